// Round 3
// baseline (367.591 us; speedup 1.0000x reference)
//
#include <hip/hip_runtime.h>
#include <math.h>

#define RFL(x) __builtin_amdgcn_readfirstlane(x)

// LIF: v = v + (x - v)/2 ; s = (v >= 1) ; v = s ? 0 : v   (exact rounding match, no contraction)
static __device__ __forceinline__ float lif_upd(float& v, float x) {
  v = __fadd_rn(v, __fmul_rn(__fsub_rn(x, v), 0.5f));
  float s = (v >= 1.0f) ? 1.0f : 0.0f;
  v = (v >= 1.0f) ? 0.0f : v;
  return s;
}

// Zero the 1-element halo ring of 2048 padded [W][W] planes.
template<int W>
__global__ __launch_bounds__(256) void k_zhalo(float* __restrict__ buf) {
  constexpr int PERIM = 4 * W - 4;
  int id = blockIdx.x * 256 + threadIdx.x;
  if (id >= 2048 * PERIM) return;
  int pl = id / PERIM, p = id % PERIM;
  int row, col;
  if (p < W)            { row = 0;     col = p; }
  else if (p < 2 * W)   { row = W - 1; col = p - W; }
  else { int q = p - 2 * W; row = 1 + (q >> 1); col = (q & 1) ? (W - 1) : 0; }
  buf[pl * (W * W) + row * W + col] = 0.f;
}

// Layer 0: fused conv(2->64, 128x128, SAME) + BN + LIF + 2x2 maxpool.
// co-blocked: 4 output channels x 1 pooled px per thread; t-loop internal, v in regs.
// out: padded spikes [4][8][64][66][66] (interior at +1,+1)
__global__ __launch_bounds__(256, 4) void k_conv0(
    const float* __restrict__ x,   // [8][4][2][128][128]
    const float* __restrict__ w,   // [64][2][3][3]
    const float* __restrict__ bng, const float* __restrict__ bnb,
    const float* __restrict__ bnm, const float* __restrict__ bnv,
    float* __restrict__ out)
{
  int id = blockIdx.x * 256 + threadIdx.x;
  int pp  = id & 4095;             // 64x64 pooled positions
  int cog = RFL((id >> 12) & 15);  // 4-channel group
  int n   = RFL(id >> 16);
  int py = pp >> 6, px = pp & 63;

  float gsc[4], bias[4];
  #pragma unroll
  for (int j = 0; j < 4; ++j) {
    int co = cog * 4 + j;
    float inv = 1.0f / sqrtf(bnv[co] + 1e-5f);
    gsc[j]  = __fmul_rn(bng[co], inv);
    bias[j] = __fsub_rn(bnb[co], __fmul_rn(__fmul_rn(bnm[co], bng[co]), inv));
  }

  bool lv  = (px >= 1);
  bool rv2 = (px <= 62);

  float vm[4][4];
  #pragma unroll
  for (int j = 0; j < 4; ++j)
    #pragma unroll
    for (int q = 0; q < 4; ++q) vm[j][q] = 0.f;

  #pragma unroll 1
  for (int t = 0; t < 4; ++t) {
    float s[4][4];
    #pragma unroll
    for (int j = 0; j < 4; ++j)
      #pragma unroll
      for (int q = 0; q < 4; ++q) s[j][q] = 0.f;

    #pragma unroll
    for (int ci = 0; ci < 2; ++ci) {
      const float* pl = x + ((n * 4 + t) * 2 + ci) * 16384;
      // q cols cover 2px-2 .. 2px+3 (even-aligned float2 triplets), rows 2py-1 .. 2py+2
      float q[4][6];
      #pragma unroll
      for (int i = 0; i < 4; ++i) {
        int r = 2 * py - 1 + i;
        bool rok = (unsigned)r < 128u;
        const float* rowp = pl + r * 128 + 2 * px;
        float2 m  = rok          ? *(const float2*)(rowp)     : make_float2(0.f, 0.f);
        float2 lft= (rok && lv)  ? *(const float2*)(rowp - 2) : make_float2(0.f, 0.f);
        float2 rgt= (rok && rv2) ? *(const float2*)(rowp + 2) : make_float2(0.f, 0.f);
        q[i][0] = lft.x; q[i][1] = lft.y; q[i][2] = m.x;
        q[i][3] = m.y;   q[i][4] = rgt.x; q[i][5] = rgt.y;
      }
      #pragma unroll
      for (int j = 0; j < 4; ++j) {
        const float* wp = w + (cog * 4 + j) * 18 + ci * 9;
        #pragma unroll
        for (int ky = 0; ky < 3; ++ky)
          #pragma unroll
          for (int kx = 0; kx < 3; ++kx) {
            float wv = wp[ky * 3 + kx];
            s[j][0] = fmaf(q[ky    ][kx + 1], wv, s[j][0]);
            s[j][1] = fmaf(q[ky    ][kx + 2], wv, s[j][1]);
            s[j][2] = fmaf(q[ky + 1][kx + 1], wv, s[j][2]);
            s[j][3] = fmaf(q[ky + 1][kx + 2], wv, s[j][3]);
          }
      }
    }
    #pragma unroll
    for (int j = 0; j < 4; ++j) {
      float h0 = __fadd_rn(__fmul_rn(s[j][0], gsc[j]), bias[j]);
      float h1 = __fadd_rn(__fmul_rn(s[j][1], gsc[j]), bias[j]);
      float h2 = __fadd_rn(__fmul_rn(s[j][2], gsc[j]), bias[j]);
      float h3 = __fadd_rn(__fmul_rn(s[j][3], gsc[j]), bias[j]);
      float sp = fmaxf(fmaxf(lif_upd(vm[j][0], h0), lif_upd(vm[j][1], h1)),
                       fmaxf(lif_upd(vm[j][2], h2), lif_upd(vm[j][3], h3)));
      out[(((t * 8 + n) * 64 + cog * 4 + j) * 66 + (py + 1)) * 66 + (px + 1)] = sp;
    }
  }
}

// Conv (64->64, HxH, SAME) + BN, t-parallel, co-blocked, float2 input loads (TPX==2).
// CO_B output channels x TPYx2 pixels per thread. Weights wave-uniform -> scalar loads.
// Requires TILES multiple of 64.
template<int H, int CO_B, int TPY, int MINW>
__global__ __launch_bounds__(256, MINW) void k_convB(
    const float* __restrict__ in,   // [4][8][64][H+2][H+2] padded spikes
    const float* __restrict__ w,    // [64][64][3][3] (layer slice)
    const float* __restrict__ bng, const float* __restrict__ bnb,
    const float* __restrict__ bnm, const float* __restrict__ bnv,
    float* __restrict__ pre)        // [4][8][64][H][H]
{
  constexpr int TPX = 2;
  constexpr int W2 = H + 2;
  constexpr int TX = H / TPX;
  constexpr int TY = H / TPY;
  constexpr int TILES = TX * TY;
  constexpr int NCOG = 64 / CO_B;
  static_assert(TILES % 64 == 0, "cog must be wave-uniform");

  int id = blockIdx.x * 256 + threadIdx.x;
  int tile = id % TILES;
  int rest = id / TILES;
  int cog = RFL(rest % NCOG);
  int t   = RFL((rest / NCOG) & 3);
  int n   = RFL(rest / (NCOG * 4));
  int tx = tile % TX, ty = tile / TX;
  int x0 = tx * TPX, y0 = ty * TPY;

  float gsc[CO_B], bias[CO_B];
  #pragma unroll
  for (int j = 0; j < CO_B; ++j) {
    int co = cog * CO_B + j;
    float inv = 1.0f / sqrtf(bnv[co] + 1e-5f);
    gsc[j]  = __fmul_rn(bng[co], inv);
    bias[j] = __fsub_rn(bnb[co], __fmul_rn(__fmul_rn(bnm[co], bng[co]), inv));
  }

  const float* ib = in + ((t * 8 + n) * 64) * (W2 * W2) + y0 * W2 + x0;
  const float* wb = w + (cog * CO_B) * 576;

  float acc[CO_B][TPY * TPX];
  #pragma unroll
  for (int j = 0; j < CO_B; ++j)
    #pragma unroll
    for (int q = 0; q < TPY * TPX; ++q) acc[j][q] = 0.f;

  #pragma unroll 1
  for (int ci = 0; ci < 64; ++ci) {
    const float* pl = ib + ci * (W2 * W2);
    float p[TPY + 2][4];
    #pragma unroll
    for (int i = 0; i < TPY + 2; ++i) {
      const float* rowp = pl + i * W2;       // (y0+i, x0) in padded coords, 8B aligned
      float2 u0 = *(const float2*)(rowp);
      float2 u1 = *(const float2*)(rowp + 2);
      p[i][0] = u0.x; p[i][1] = u0.y; p[i][2] = u1.x; p[i][3] = u1.y;
    }
    #pragma unroll
    for (int j = 0; j < CO_B; ++j) {
      const float* wp = wb + j * 576 + ci * 9;
      #pragma unroll
      for (int ky = 0; ky < 3; ++ky)
        #pragma unroll
        for (int kx = 0; kx < 3; ++kx) {
          float wv = wp[ky * 3 + kx];
          #pragma unroll
          for (int a = 0; a < TPY; ++a)
            #pragma unroll
            for (int b = 0; b < TPX; ++b)
              acc[j][a * TPX + b] = fmaf(p[a + ky][b + kx], wv, acc[j][a * TPX + b]);
        }
    }
  }
  #pragma unroll
  for (int j = 0; j < CO_B; ++j) {
    float* ob = pre + ((t * 8 + n) * 64 + cog * CO_B + j) * (H * H) + y0 * H + x0;
    #pragma unroll
    for (int a = 0; a < TPY; ++a)
      #pragma unroll
      for (int b = 0; b < TPX; ++b)
        ob[a * H + b] = __fadd_rn(__fmul_rn(acc[j][a * TPX + b], gsc[j]), bias[j]);
  }
}

// Old-style conv for H=8 (TILES=16 -> K=64 keeps co wave-uniform).
template<int H, int TP>
__global__ __launch_bounds__(256) void k_conv(
    const float* __restrict__ in, const float* __restrict__ w,
    const float* __restrict__ bng, const float* __restrict__ bnb,
    const float* __restrict__ bnm, const float* __restrict__ bnv,
    float* __restrict__ pre)
{
  constexpr int W2 = H + 2;
  constexpr int TX = H / TP;
  constexpr int TILES = TX * TX;
  constexpr int K = 4 * TILES;
  int id = blockIdx.x * 256 + threadIdx.x;
  int k  = id % K;
  int co = RFL((id / K) & 63);
  int n  = RFL(id / (K * 64));
  int t    = k / TILES;
  int tile = k % TILES;
  int y0 = (tile / TX) * TP;
  int x0 = (tile % TX) * TP;

  float inv  = 1.0f / sqrtf(bnv[co] + 1e-5f);
  float gsc  = __fmul_rn(bng[co], inv);
  float bias = __fsub_rn(bnb[co], __fmul_rn(__fmul_rn(bnm[co], bng[co]), inv));

  const float* wb = w + co * 576;
  const float* ib = in + ((t * 8 + n) * 64) * (W2 * W2) + y0 * W2 + x0;

  float acc[TP * TP];
  #pragma unroll
  for (int q = 0; q < TP * TP; ++q) acc[q] = 0.f;

  #pragma unroll 1
  for (int ci = 0; ci < 64; ++ci) {
    const float* pl = ib + ci * (W2 * W2);
    float p[TP + 2][TP + 2];
    #pragma unroll
    for (int i = 0; i < TP + 2; ++i)
      #pragma unroll
      for (int j = 0; j < TP + 2; ++j)
        p[i][j] = pl[i * W2 + j];
    const float* wp = wb + ci * 9;
    #pragma unroll
    for (int ky = 0; ky < 3; ++ky)
      #pragma unroll
      for (int kx = 0; kx < 3; ++kx) {
        float wv = wp[ky * 3 + kx];
        #pragma unroll
        for (int a = 0; a < TP; ++a)
          #pragma unroll
          for (int b = 0; b < TP; ++b)
            acc[a * TP + b] = fmaf(p[a + ky][b + kx], wv, acc[a * TP + b]);
      }
  }
  float* ob = pre + ((t * 8 + n) * 64 + co) * (H * H) + y0 * H + x0;
  #pragma unroll
  for (int a = 0; a < TP; ++a)
    #pragma unroll
    for (int b = 0; b < TP; ++b)
      ob[a * H + b] = __fadd_rn(__fmul_rn(acc[a * TP + b], gsc), bias);
}

// LIF (t-sequential, v in registers) + 2x2 maxpool over pre-activations.
template<int H, bool PADOUT>
__global__ __launch_bounds__(256) void k_lifpool(
    const float* __restrict__ pre,  // [4][8][64][H][H]
    float* __restrict__ out)        // PADOUT: [4][8][64][H/2+2][H/2+2] else flat
{
  constexpr int Hp = H / 2;
  constexpr int PP = Hp * Hp;
  int id = blockIdx.x * 256 + threadIdx.x;
  int pp = id % PP;
  int co = (id / PP) & 63;
  int n  = id / (PP * 64);
  int py = pp / Hp, px = pp % Hp;
  float v0 = 0.f, v1 = 0.f, v2 = 0.f, v3 = 0.f;
  #pragma unroll 1
  for (int t = 0; t < 4; ++t) {
    const float* pb = pre + ((t * 8 + n) * 64 + co) * (H * H) + (2 * py) * H + 2 * px;
    float sp = fmaxf(fmaxf(lif_upd(v0, pb[0]), lif_upd(v1, pb[1])),
                     fmaxf(lif_upd(v2, pb[H]), lif_upd(v3, pb[H + 1])));
    if (PADOUT)
      out[(((t * 8 + n) * 64 + co) * (Hp + 2) + (py + 1)) * (Hp + 2) + (px + 1)] = sp;
    else
      out[((t * 8 + n) * 64 + co) * PP + pp] = sp;
  }
}

// FC1: (8,1024)@(256,1024)^T + LIF, one wave per (n,j), weights cached in 16 regs across t.
__global__ __launch_bounds__(256) void k_fc1(
    const float* __restrict__ s4, const float* __restrict__ w, float* __restrict__ out)
{
  int wv = blockIdx.x * 4 + (threadIdx.x >> 6);
  int lane = threadIdx.x & 63;
  int j = wv & 255;
  int n = wv >> 8;
  float wr[16];
  #pragma unroll
  for (int u = 0; u < 16; ++u) wr[u] = w[j * 1024 + u * 64 + lane];
  float v = 0.f;
  #pragma unroll 1
  for (int t = 0; t < 4; ++t) {
    const float* sp = s4 + (t * 8 + n) * 1024;
    float sum = 0.f;
    #pragma unroll
    for (int u = 0; u < 16; ++u) sum = fmaf(wr[u], sp[u * 64 + lane], sum);
    #pragma unroll
    for (int off = 32; off > 0; off >>= 1) sum += __shfl_xor(sum, off, 64);
    float s = lif_upd(v, sum);
    if (lane == 0) out[(t * 8 + n) * 256 + j] = s;
  }
}

// FC2: (8,256)@(110,256)^T + LIF.
__global__ __launch_bounds__(256) void k_fc2(
    const float* __restrict__ s1, const float* __restrict__ w, float* __restrict__ out)
{
  int wv = blockIdx.x * 4 + (threadIdx.x >> 6);
  int lane = threadIdx.x & 63;
  int j = wv % 110;
  int n = wv / 110;
  float wr[4];
  #pragma unroll
  for (int u = 0; u < 4; ++u) wr[u] = w[j * 256 + u * 64 + lane];
  float v = 0.f;
  #pragma unroll 1
  for (int t = 0; t < 4; ++t) {
    const float* sp = s1 + (t * 8 + n) * 256;
    float sum = 0.f;
    #pragma unroll
    for (int u = 0; u < 4; ++u) sum = fmaf(wr[u], sp[u * 64 + lane], sum);
    #pragma unroll
    for (int off = 32; off > 0; off >>= 1) sum += __shfl_xor(sum, off, 64);
    float s = lif_upd(v, sum);
    if (lane == 0) out[(t * 8 + n) * 110 + j] = s;
  }
}

// acc[n][g] = sum_t mean_{j<10} s2[t][n][g*10+j]
__global__ __launch_bounds__(128) void k_acc(const float* __restrict__ s2, float* __restrict__ out) {
  int id = threadIdx.x;
  if (id >= 88) return;
  int n = id / 11, g = id % 11;
  float a = 0.f;
  #pragma unroll 1
  for (int t = 0; t < 4; ++t) {
    float m = 0.f;
    #pragma unroll
    for (int jj = 0; jj < 10; ++jj) m = __fadd_rn(m, s2[(t * 8 + n) * 110 + g * 10 + jj]);
    a = __fadd_rn(a, __fdiv_rn(m, 10.0f));
  }
  out[n * 11 + g] = a;
}

extern "C" void kernel_launch(void* const* d_in, const int* in_sizes, int n_in,
                              void* d_out, int out_size, void* d_ws, size_t ws_size,
                              hipStream_t stream)
{
  const float* x  = (const float*)d_in[0];
  const float* w0 = (const float*)d_in[1];
  const float* wc = (const float*)d_in[2];
  const float* bg = (const float*)d_in[3];
  const float* bb = (const float*)d_in[4];
  const float* bm = (const float*)d_in[5];
  const float* bv = (const float*)d_in[6];
  const float* w1 = (const float*)d_in[7];
  const float* w2 = (const float*)d_in[8];
  float* out = (float*)d_out;
  float* ws  = (float*)d_ws;

  // workspace layout (float offsets); padded spike buffers first (halo-zeroed)
  float* buf0 = ws + 0;         // [4][8][64][66][66] = 8,921,088
  float* buf1 = ws + 8921088;   // [4][8][64][34][34] = 2,367,488
  float* buf2 = ws + 11288576;  // [4][8][64][18][18] =   663,552
  float* buf3 = ws + 11952128;  // [4][8][64][10][10] =   204,800
  float* buf4 = ws + 12156928;  // [4][8][1024]       =    32,768  (flat, fc input)
  float* pre1 = ws + 12189696;  // [4][8][64][64][64] = 8,388,608
  float* pre2 = ws + 20578304;  // [4][8][64][32][32] = 2,097,152
  float* pre3 = ws + 22675456;  // [4][8][64][16][16] =   524,288
  float* pre4 = ws + 23199744;  // [4][8][64][8][8]   =   131,072
  float* s1   = ws + 23330816;  // [4][8][256]        =     8,192
  float* s2   = ws + 23339008;  // [4][8][110]        =     3,520
  if (ws_size < (size_t)23342528 * sizeof(float)) return;  // need ~93.4 MB

  // halo zeroing only (interiors are fully overwritten each call)
  k_zhalo<66><<<(2048 * 260 + 255) / 256, 256, 0, stream>>>(buf0);
  k_zhalo<34><<<(2048 * 132 + 255) / 256, 256, 0, stream>>>(buf1);
  k_zhalo<18><<<(2048 * 68 + 255) / 256, 256, 0, stream>>>(buf2);
  k_zhalo<10><<<(2048 * 36 + 255) / 256, 256, 0, stream>>>(buf3);

  k_conv0<<<2048, 256, 0, stream>>>(x, w0, bg, bb, bm, bv, buf0);

  k_convB<64, 4, 2, 8><<<2048, 256, 0, stream>>>(buf0, wc + 0 * 36864, bg + 64,  bb + 64,  bm + 64,  bv + 64,  pre1);
  k_lifpool<64, true><<<2048, 256, 0, stream>>>(pre1, buf1);

  k_convB<32, 4, 1, 8><<<1024, 256, 0, stream>>>(buf1, wc + 1 * 36864, bg + 128, bb + 128, bm + 128, bv + 128, pre2);
  k_lifpool<32, true><<<512, 256, 0, stream>>>(pre2, buf2);

  k_convB<16, 2, 1, 8><<<512, 256, 0, stream>>>(buf2, wc + 2 * 36864, bg + 192, bb + 192, bm + 192, bv + 192, pre3);
  k_lifpool<16, true><<<128, 256, 0, stream>>>(pre3, buf3);

  k_conv<8, 2><<<128, 256, 0, stream>>>(buf3, wc + 3 * 36864, bg + 256, bb + 256, bm + 256, bv + 256, pre4);
  k_lifpool<8, false><<<32, 256, 0, stream>>>(pre4, buf4);

  k_fc1<<<512, 256, 0, stream>>>(buf4, w1, s1);
  k_fc2<<<220, 256, 0, stream>>>(s1, w2, s2);
  k_acc<<<1, 128, 0, stream>>>(s2, out);
}

// Round 4
// 316.366 us; speedup vs baseline: 1.1619x; 1.1619x over previous
//
#include <hip/hip_runtime.h>
#include <hip/hip_bf16.h>
#include <math.h>

#define RFL(x) __builtin_amdgcn_readfirstlane(x)

typedef short bfrag __attribute__((ext_vector_type(8)));   // 8 bf16 (4 VGPR)
typedef float ffrag __attribute__((ext_vector_type(4)));   // 4 f32 acc

// LIF: v = v + (x - v)/2 ; s = (v >= 1) ; v = s ? 0 : v   (exact rounding match)
static __device__ __forceinline__ float lif_upd(float& v, float x) {
  v = __fadd_rn(v, __fmul_rn(__fsub_rn(x, v), 0.5f));
  float s = (v >= 1.0f) ? 1.0f : 0.0f;
  v = (v >= 1.0f) ? 0.0f : v;
  return s;
}

static __device__ __forceinline__ unsigned short f2bf(float x) {
  __hip_bfloat16 h = __float2bfloat16(x);
  return *reinterpret_cast<unsigned short*>(&h);
}
static __device__ __forceinline__ float bf2f(unsigned short u) {
  __hip_bfloat16 h = *reinterpret_cast<__hip_bfloat16*>(&u);
  return __bfloat162float(h);
}

// Split conv weights (4 layers, 64x64x3x3 f32) into 3 bf16 components, transposed to
// wt[((l*3+s)*9+tap)*4096 + co*64 + ci]  (B-fragment friendly: contiguous in ci).
__global__ __launch_bounds__(256) void k_wsplit(const float* __restrict__ wc,
                                                unsigned short* __restrict__ wt) {
  int id = blockIdx.x * 256 + threadIdx.x;   // 147456 total
  int tap = id % 9; int r = id / 9;
  int ci = r & 63; r >>= 6;
  int co = r & 63; int l = r >> 6;
  float w = wc[(size_t)(((l * 64 + co) * 64 + ci) * 9) + tap];
  unsigned short h0 = f2bf(w);  float r1 = __fsub_rn(w, bf2f(h0));
  unsigned short h1 = f2bf(r1); float r2 = __fsub_rn(r1, bf2f(h1));
  unsigned short h2 = f2bf(r2);
  size_t base = (size_t)((l * 3) * 9 + tap) * 4096 + co * 64 + ci;
  wt[base] = h0;
  wt[base + 9 * 4096] = h1;
  wt[base + 18 * 4096] = h2;
}

// Zero the 1-pixel halo ring (x64 channels) of 32 padded [W2][W2][64] bf16 planes.
template<int W2>
__global__ __launch_bounds__(256) void k_zhalo2(unsigned short* __restrict__ buf) {
  constexpr int PERIM = 4 * W2 - 4;
  int id = blockIdx.x * 256 + threadIdx.x;       // 32*PERIM*8 threads
  int c8 = id & 7;
  int r = id >> 3;
  int p = r % PERIM; int pl = r / PERIM;
  if (pl >= 32) return;
  int row, col;
  if (p < W2)            { row = 0;      col = p; }
  else if (p < 2 * W2)   { row = W2 - 1; col = p - W2; }
  else { int q = p - 2 * W2; row = 1 + (q >> 1); col = (q & 1) ? (W2 - 1) : 0; }
  *(uint4*)(buf + ((size_t)(pl * W2 + row) * W2 + col) * 64 + c8 * 8) = make_uint4(0u, 0u, 0u, 0u);
}

// Layer 0: fused conv(2->64) + BN + LIF + 2x2 maxpool. Writes channels-last bf16 spikes
// into padded [32][66][66][64] (interior at +1,+1).
__global__ __launch_bounds__(256, 4) void k_conv0(
    const float* __restrict__ x,   // [8][4][2][128][128]
    const float* __restrict__ w,   // [64][2][3][3]
    const float* __restrict__ bng, const float* __restrict__ bnb,
    const float* __restrict__ bnm, const float* __restrict__ bnv,
    unsigned short* __restrict__ out)
{
  int id = blockIdx.x * 256 + threadIdx.x;
  int pp  = id & 4095;             // 64x64 pooled positions
  int cog = RFL((id >> 12) & 15);  // 4-channel group
  int n   = RFL(id >> 16);
  int py = pp >> 6, px = pp & 63;

  float gsc[4], bias[4];
  #pragma unroll
  for (int j = 0; j < 4; ++j) {
    int co = cog * 4 + j;
    float inv = 1.0f / sqrtf(bnv[co] + 1e-5f);
    gsc[j]  = __fmul_rn(bng[co], inv);
    bias[j] = __fsub_rn(bnb[co], __fmul_rn(__fmul_rn(bnm[co], bng[co]), inv));
  }

  bool lv  = (px >= 1);
  bool rv2 = (px <= 62);

  float vm[4][4];
  #pragma unroll
  for (int j = 0; j < 4; ++j)
    #pragma unroll
    for (int q = 0; q < 4; ++q) vm[j][q] = 0.f;

  #pragma unroll 1
  for (int t = 0; t < 4; ++t) {
    float s[4][4];
    #pragma unroll
    for (int j = 0; j < 4; ++j)
      #pragma unroll
      for (int q = 0; q < 4; ++q) s[j][q] = 0.f;

    #pragma unroll
    for (int ci = 0; ci < 2; ++ci) {
      const float* pl = x + (size_t)((n * 4 + t) * 2 + ci) * 16384;
      float q[4][6];
      #pragma unroll
      for (int i = 0; i < 4; ++i) {
        int rr = 2 * py - 1 + i;
        bool rok = (unsigned)rr < 128u;
        const float* rowp = pl + rr * 128 + 2 * px;
        float2 m  = rok          ? *(const float2*)(rowp)     : make_float2(0.f, 0.f);
        float2 lf = (rok && lv)  ? *(const float2*)(rowp - 2) : make_float2(0.f, 0.f);
        float2 rg = (rok && rv2) ? *(const float2*)(rowp + 2) : make_float2(0.f, 0.f);
        q[i][0] = lf.x; q[i][1] = lf.y; q[i][2] = m.x;
        q[i][3] = m.y;  q[i][4] = rg.x; q[i][5] = rg.y;
      }
      #pragma unroll
      for (int j = 0; j < 4; ++j) {
        const float* wp = w + (cog * 4 + j) * 18 + ci * 9;
        #pragma unroll
        for (int ky = 0; ky < 3; ++ky)
          #pragma unroll
          for (int kx = 0; kx < 3; ++kx) {
            float wv = wp[ky * 3 + kx];
            s[j][0] = fmaf(q[ky    ][kx + 1], wv, s[j][0]);
            s[j][1] = fmaf(q[ky    ][kx + 2], wv, s[j][1]);
            s[j][2] = fmaf(q[ky + 1][kx + 1], wv, s[j][2]);
            s[j][3] = fmaf(q[ky + 1][kx + 2], wv, s[j][3]);
          }
      }
    }
    ushort4 u4;
    unsigned short us[4];
    #pragma unroll
    for (int j = 0; j < 4; ++j) {
      float h0 = __fadd_rn(__fmul_rn(s[j][0], gsc[j]), bias[j]);
      float h1 = __fadd_rn(__fmul_rn(s[j][1], gsc[j]), bias[j]);
      float h2 = __fadd_rn(__fmul_rn(s[j][2], gsc[j]), bias[j]);
      float h3 = __fadd_rn(__fmul_rn(s[j][3], gsc[j]), bias[j]);
      float sp = fmaxf(fmaxf(lif_upd(vm[j][0], h0), lif_upd(vm[j][1], h1)),
                       fmaxf(lif_upd(vm[j][2], h2), lif_upd(vm[j][3], h3)));
      us[j] = (sp >= 0.5f) ? (unsigned short)0x3F80 : (unsigned short)0;
    }
    u4.x = us[0]; u4.y = us[1]; u4.z = us[2]; u4.w = us[3];
    size_t pix = (size_t)((t * 8 + n) * 66 + (py + 1)) * 66 + (px + 1);
    *(ushort4*)(out + pix * 64 + cog * 4) = u4;
  }
}

// MFMA conv(64->64) + BN + LIF + 2x2 pool, fused over t (v in regs).
// Wave: 16 x-cols (x0..x0+15) x YS y-rows x 16 co. A row = lane&15 = x-offset,
// k = (lane>>4)*8+e = ci. acc row (lane>>4)*4+j = x-offset, col lane&15 = co.
template<int H, int YS>
__global__ __launch_bounds__(256, 2) void k_convM(
    const unsigned short* __restrict__ in,   // [32][H+2][H+2][64] bf16 spikes (padded)
    const unsigned short* __restrict__ wtl,  // [3][9][64][64] bf16 (this layer)
    const float* __restrict__ bng, const float* __restrict__ bnb,
    const float* __restrict__ bnm, const float* __restrict__ bnv,
    unsigned short* __restrict__ osp)        // [32][H/2+2][H/2+2][64] bf16 (padded)
{
  constexpr int W2 = H + 2;
  constexpr int HP2 = H / 2 + 2;
  constexpr int XT = H / 16;
  constexpr int YT = H / YS;
  int wid = (blockIdx.x * 256 + threadIdx.x) >> 6;
  int lane = threadIdx.x & 63;
  int xt = RFL(wid % XT); int r = wid / XT;
  int yt = RFL(r % YT); r = r / YT;
  int cog = RFL(r & 3); int n = RFL(r >> 2);
  int x0 = xt * 16, y0 = yt * YS;
  int col = lane & 15, kg = lane >> 4;
  int co = cog * 16 + col;
  int laneAB = col * 64 + kg * 8;

  float inv = 1.0f / sqrtf(bnv[co] + 1e-5f);
  float g  = __fmul_rn(bng[co], inv);
  float bc = __fsub_rn(bnb[co], __fmul_rn(__fmul_rn(bnm[co], bng[co]), inv));

  float v[YS][4];
  #pragma unroll
  for (int yy = 0; yy < YS; ++yy)
    #pragma unroll
    for (int j = 0; j < 4; ++j) v[yy][j] = 0.f;

  #pragma unroll 1
  for (int t = 0; t < 4; ++t) {
    const unsigned short* ibase = in + (size_t)(t * 8 + n) * (W2 * W2 * 64);
    ffrag acc[YS];
    #pragma unroll
    for (int yy = 0; yy < YS; ++yy) {
      acc[yy][0] = 0.f; acc[yy][1] = 0.f; acc[yy][2] = 0.f; acc[yy][3] = 0.f;
    }
    #pragma unroll
    for (int tap = 0; tap < 9; ++tap) {
      const int ky = tap / 3, kx = tap % 3;
      #pragma unroll
      for (int kh = 0; kh < 2; ++kh) {
        bfrag av[YS];
        #pragma unroll
        for (int yy = 0; yy < YS; ++yy) {
          const unsigned short* au = ibase + ((y0 + yy + ky) * W2 + x0 + kx) * 64 + kh * 32;
          av[yy] = *(const bfrag*)(au + laneAB);
        }
        #pragma unroll
        for (int s = 0; s < 3; ++s) {
          const unsigned short* wu = wtl + (s * 9 + tap) * 4096 + cog * 1024 + kh * 32;
          bfrag bv = *(const bfrag*)(wu + laneAB);
          #pragma unroll
          for (int yy = 0; yy < YS; ++yy)
            acc[yy] = __builtin_amdgcn_mfma_f32_16x16x32_bf16(av[yy], bv, acc[yy], 0, 0, 0);
        }
      }
    }
    // BN + LIF + 2x2 pool (x-pairs within lane j, y-pairs across acc sets)
    #pragma unroll
    for (int yy = 0; yy < YS; yy += 2) {
      float s0[4], s1[4];
      #pragma unroll
      for (int j = 0; j < 4; ++j) {
        float h0 = __fadd_rn(__fmul_rn(acc[yy][j], g), bc);
        s0[j] = lif_upd(v[yy][j], h0);
        float h1 = __fadd_rn(__fmul_rn(acc[yy + 1][j], g), bc);
        s1[j] = lif_upd(v[yy + 1][j], h1);
      }
      #pragma unroll
      for (int b2 = 0; b2 < 2; ++b2) {
        float m = fmaxf(fmaxf(s0[2 * b2], s0[2 * b2 + 1]),
                        fmaxf(s1[2 * b2], s1[2 * b2 + 1]));
        int py = (y0 + yy) >> 1;
        int px = (x0 >> 1) + kg * 2 + b2;
        osp[(size_t)(((t * 8 + n) * HP2 + py + 1) * HP2 + (px + 1)) * 64 + co] =
            (m >= 0.5f) ? (unsigned short)0x3F80 : (unsigned short)0;
      }
    }
  }
}

// Layer 4 (8x8): scalar conv + BN, reads channels-last bf16 spikes, writes channels-first f32 pre.
__global__ __launch_bounds__(256) void k_conv4(
    const unsigned short* __restrict__ in,  // [32][10][10][64] bf16
    const float* __restrict__ w,            // [64][64][3][3] layer slice (f32)
    const float* __restrict__ bng, const float* __restrict__ bnb,
    const float* __restrict__ bnm, const float* __restrict__ bnv,
    float* __restrict__ pre)                // [32][64][8][8]
{
  int id = blockIdx.x * 256 + threadIdx.x;   // 32768
  int k = id & 63;
  int co = RFL((id >> 6) & 63);
  int n = RFL(id >> 12);
  int t = k >> 4; int tile = k & 15;
  int y0 = (tile >> 2) * 2, x0 = (tile & 3) * 2;

  float inv  = 1.0f / sqrtf(bnv[co] + 1e-5f);
  float gsc  = __fmul_rn(bng[co], inv);
  float bias = __fsub_rn(bnb[co], __fmul_rn(__fmul_rn(bnm[co], bng[co]), inv));

  const float* wb = w + co * 576;
  const unsigned short* ib = in + ((size_t)((t * 8 + n) * 10 + y0) * 10 + x0) * 64;

  float acc[4] = {0.f, 0.f, 0.f, 0.f};
  #pragma unroll 1
  for (int ci = 0; ci < 64; ++ci) {
    float p[4][4];
    #pragma unroll
    for (int i = 0; i < 4; ++i)
      #pragma unroll
      for (int j = 0; j < 4; ++j)
        p[i][j] = bf2f(ib[(i * 10 + j) * 64 + ci]);
    const float* wp = wb + ci * 9;
    #pragma unroll
    for (int ky = 0; ky < 3; ++ky)
      #pragma unroll
      for (int kx = 0; kx < 3; ++kx) {
        float wv = wp[ky * 3 + kx];
        acc[0] = fmaf(p[ky][kx],         wv, acc[0]);
        acc[1] = fmaf(p[ky][kx + 1],     wv, acc[1]);
        acc[2] = fmaf(p[ky + 1][kx],     wv, acc[2]);
        acc[3] = fmaf(p[ky + 1][kx + 1], wv, acc[3]);
      }
  }
  float* ob = pre + ((size_t)(t * 8 + n) * 64 + co) * 64 + y0 * 8 + x0;
  ob[0] = __fadd_rn(__fmul_rn(acc[0], gsc), bias);
  ob[1] = __fadd_rn(__fmul_rn(acc[1], gsc), bias);
  ob[8] = __fadd_rn(__fmul_rn(acc[2], gsc), bias);
  ob[9] = __fadd_rn(__fmul_rn(acc[3], gsc), bias);
}

// LIF + 2x2 pool for layer 4; writes channels-last f32 [32][16][64] (fc input).
__global__ __launch_bounds__(256) void k_lifpool8(const float* __restrict__ pre,
                                                  float* __restrict__ out) {
  int id = blockIdx.x * 256 + threadIdx.x;  // 8192
  int pp = id & 15; int co = (id >> 4) & 63; int n = id >> 10;
  int py = pp >> 2, px = pp & 3;
  float v0 = 0.f, v1 = 0.f, v2 = 0.f, v3 = 0.f;
  #pragma unroll 1
  for (int t = 0; t < 4; ++t) {
    const float* pb = pre + ((size_t)(t * 8 + n) * 64 + co) * 64 + 2 * py * 8 + 2 * px;
    float sp = fmaxf(fmaxf(lif_upd(v0, pb[0]), lif_upd(v1, pb[1])),
                     fmaxf(lif_upd(v2, pb[8]), lif_upd(v3, pb[9])));
    out[(size_t)((t * 8 + n) * 16 + pp) * 64 + co] = sp;
  }
}

// FC1: input channels-last (s*64+c), weight index c*16+s -> per-lane contiguous 16 floats.
__global__ __launch_bounds__(256) void k_fc1(
    const float* __restrict__ s4, const float* __restrict__ w, float* __restrict__ out)
{
  int wv = blockIdx.x * 4 + (threadIdx.x >> 6);
  int lane = threadIdx.x & 63;
  int j = wv & 255;
  int n = wv >> 8;
  float wr[16];
  #pragma unroll
  for (int u = 0; u < 16; ++u) wr[u] = w[j * 1024 + lane * 16 + u];
  float v = 0.f;
  #pragma unroll 1
  for (int t = 0; t < 4; ++t) {
    const float* sp = s4 + (t * 8 + n) * 1024;
    float sum = 0.f;
    #pragma unroll
    for (int u = 0; u < 16; ++u) sum = fmaf(wr[u], sp[u * 64 + lane], sum);
    #pragma unroll
    for (int off = 32; off > 0; off >>= 1) sum += __shfl_xor(sum, off, 64);
    float s = lif_upd(v, sum);
    if (lane == 0) out[(t * 8 + n) * 256 + j] = s;
  }
}

// FC2: (8,256)@(110,256)^T + LIF.
__global__ __launch_bounds__(256) void k_fc2(
    const float* __restrict__ s1, const float* __restrict__ w, float* __restrict__ out)
{
  int wv = blockIdx.x * 4 + (threadIdx.x >> 6);
  int lane = threadIdx.x & 63;
  int j = wv % 110;
  int n = wv / 110;
  float wr[4];
  #pragma unroll
  for (int u = 0; u < 4; ++u) wr[u] = w[j * 256 + u * 64 + lane];
  float v = 0.f;
  #pragma unroll 1
  for (int t = 0; t < 4; ++t) {
    const float* sp = s1 + (t * 8 + n) * 256;
    float sum = 0.f;
    #pragma unroll
    for (int u = 0; u < 4; ++u) sum = fmaf(wr[u], sp[u * 64 + lane], sum);
    #pragma unroll
    for (int off = 32; off > 0; off >>= 1) sum += __shfl_xor(sum, off, 64);
    float s = lif_upd(v, sum);
    if (lane == 0) out[(t * 8 + n) * 110 + j] = s;
  }
}

// acc[n][g] = sum_t mean_{j<10} s2[t][n][g*10+j]
__global__ __launch_bounds__(128) void k_acc(const float* __restrict__ s2, float* __restrict__ out) {
  int id = threadIdx.x;
  if (id >= 88) return;
  int n = id / 11, g = id % 11;
  float a = 0.f;
  #pragma unroll 1
  for (int t = 0; t < 4; ++t) {
    float m = 0.f;
    #pragma unroll
    for (int jj = 0; jj < 10; ++jj) m = __fadd_rn(m, s2[(t * 8 + n) * 110 + g * 10 + jj]);
    a = __fadd_rn(a, __fdiv_rn(m, 10.0f));
  }
  out[n * 11 + g] = a;
}

extern "C" void kernel_launch(void* const* d_in, const int* in_sizes, int n_in,
                              void* d_out, int out_size, void* d_ws, size_t ws_size,
                              hipStream_t stream)
{
  const float* x  = (const float*)d_in[0];
  const float* w0 = (const float*)d_in[1];
  const float* wc = (const float*)d_in[2];
  const float* bg = (const float*)d_in[3];
  const float* bb = (const float*)d_in[4];
  const float* bm = (const float*)d_in[5];
  const float* bv = (const float*)d_in[6];
  const float* w1 = (const float*)d_in[7];
  const float* w2 = (const float*)d_in[8];
  float* out = (float*)d_out;

  // ---- workspace layout ----
  // bf16 (ushort) region first:
  unsigned short* sp0 = (unsigned short*)d_ws;      // [32][66][66][64]  8,921,088
  unsigned short* sp1 = sp0 + 8921088;              // [32][34][34][64]  2,367,488
  unsigned short* sp2 = sp1 + 2367488;              // [32][18][18][64]    663,552
  unsigned short* sp3 = sp2 + 663552;               // [32][10][10][64]    204,800
  unsigned short* wt  = sp3 + 204800;               // [4][3][9][4096]     442,368
  // f32 region (byte offset 25,198,592; 16B aligned):
  float* fbase = (float*)((char*)d_ws + 25198592);
  float* sp4  = fbase;            // [32][16][64]  32,768
  float* pre4 = sp4 + 32768;      // [32][64][8][8] 131,072
  float* s1   = pre4 + 131072;    // [32][256]       8,192
  float* s2   = s1 + 8192;        // [32][110]       3,520
  if (ws_size < (size_t)25900800) return;

  constexpr int WTL = 3 * 9 * 4096;   // per-layer wt stride (ushorts)

  k_wsplit<<<576, 256, 0, stream>>>(wc, wt);
  k_zhalo2<66><<<260, 256, 0, stream>>>(sp0);
  k_zhalo2<34><<<132, 256, 0, stream>>>(sp1);
  k_zhalo2<18><<<68, 256, 0, stream>>>(sp2);
  k_zhalo2<10><<<36, 256, 0, stream>>>(sp3);

  k_conv0<<<2048, 256, 0, stream>>>(x, w0, bg, bb, bm, bv, sp0);

  k_convM<64, 4><<<512, 256, 0, stream>>>(sp0, wt + 0 * WTL, bg + 64,  bb + 64,  bm + 64,  bv + 64,  sp1);
  k_convM<32, 2><<<256, 256, 0, stream>>>(sp1, wt + 1 * WTL, bg + 128, bb + 128, bm + 128, bv + 128, sp2);
  k_convM<16, 2><<<64, 256, 0, stream>>>(sp2, wt + 2 * WTL, bg + 192, bb + 192, bm + 192, bv + 192, sp3);

  k_conv4<<<128, 256, 0, stream>>>(sp3, wc + 3 * 36864, bg + 256, bb + 256, bm + 256, bv + 256, pre4);
  k_lifpool8<<<32, 256, 0, stream>>>(pre4, sp4);

  k_fc1<<<512, 256, 0, stream>>>(sp4, w1, s1);
  k_fc2<<<220, 256, 0, stream>>>(s1, w2, s2);
  k_acc<<<1, 128, 0, stream>>>(s2, out);
}

// Round 5
// 235.316 us; speedup vs baseline: 1.5621x; 1.3444x over previous
//
#include <hip/hip_runtime.h>
#include <hip/hip_bf16.h>
#include <math.h>

#define RFL(x) __builtin_amdgcn_readfirstlane(x)

typedef short bfrag __attribute__((ext_vector_type(8)));   // 8 bf16 (4 VGPR)
typedef float ffrag __attribute__((ext_vector_type(4)));   // 4 f32 acc

// LIF: v = v + (x - v)/2 ; s = (v >= 1) ; v = s ? 0 : v   (exact rounding match)
static __device__ __forceinline__ float lif_upd(float& v, float x) {
  v = __fadd_rn(v, __fmul_rn(__fsub_rn(x, v), 0.5f));
  float s = (v >= 1.0f) ? 1.0f : 0.0f;
  v = (v >= 1.0f) ? 0.0f : v;
  return s;
}

static __device__ __forceinline__ unsigned short f2bf(float x) {
  __hip_bfloat16 h = __float2bfloat16(x);
  return *reinterpret_cast<unsigned short*>(&h);
}
static __device__ __forceinline__ float bf2f(unsigned short u) {
  __hip_bfloat16 h = *reinterpret_cast<__hip_bfloat16*>(&u);
  return __bfloat162float(h);
}

// Split conv weights (4 layers, 64x64x3x3 f32) into 3 bf16 components, transposed to
// wt[((l*3+s)*9+tap)*4096 + co*64 + ci]  (B-fragment friendly: contiguous in ci).
__global__ __launch_bounds__(256) void k_wsplit(const float* __restrict__ wc,
                                                unsigned short* __restrict__ wt) {
  int id = blockIdx.x * 256 + threadIdx.x;   // 147456 total
  int tap = id % 9; int r = id / 9;
  int ci = r & 63; r >>= 6;
  int co = r & 63; int l = r >> 6;
  float w = wc[(size_t)(((l * 64 + co) * 64 + ci) * 9) + tap];
  unsigned short h0 = f2bf(w);  float r1 = __fsub_rn(w, bf2f(h0));
  unsigned short h1 = f2bf(r1); float r2 = __fsub_rn(r1, bf2f(h1));
  unsigned short h2 = f2bf(r2);
  size_t base = (size_t)((l * 3) * 9 + tap) * 4096 + co * 64 + ci;
  wt[base] = h0;
  wt[base + 9 * 4096] = h1;
  wt[base + 18 * 4096] = h2;
}

// Zero the 1-pixel halo ring (x64 channels) of 32 padded [W2][W2][64] bf16 planes.
template<int W2>
__global__ __launch_bounds__(256) void k_zhalo2(unsigned short* __restrict__ buf) {
  constexpr int PERIM = 4 * W2 - 4;
  int id = blockIdx.x * 256 + threadIdx.x;       // 32*PERIM*8 threads
  int c8 = id & 7;
  int r = id >> 3;
  int p = r % PERIM; int pl = r / PERIM;
  if (pl >= 32) return;
  int row, col;
  if (p < W2)            { row = 0;      col = p; }
  else if (p < 2 * W2)   { row = W2 - 1; col = p - W2; }
  else { int q = p - 2 * W2; row = 1 + (q >> 1); col = (q & 1) ? (W2 - 1) : 0; }
  *(uint4*)(buf + ((size_t)(pl * W2 + row) * W2 + col) * 64 + c8 * 8) = make_uint4(0u, 0u, 0u, 0u);
}

// Layer 0: fused conv(2->64) + BN + LIF + 2x2 maxpool. Writes channels-last bf16 spikes
// into padded [32][66][66][64] (interior at +1,+1). n = blockIdx&7 -> XCD-local.
__global__ __launch_bounds__(256, 4) void k_conv0(
    const float* __restrict__ x,   // [8][4][2][128][128]
    const float* __restrict__ w,   // [64][2][3][3]
    const float* __restrict__ bng, const float* __restrict__ bnb,
    const float* __restrict__ bnm, const float* __restrict__ bnv,
    unsigned short* __restrict__ out)
{
  int n   = RFL(blockIdx.x & 7);
  int b2  = blockIdx.x >> 3;          // [0,256)
  int cog = RFL(b2 & 15);             // 4-channel group
  int pp  = ((b2 >> 4) << 8) | threadIdx.x;   // [0,4096) pooled positions
  int py = pp >> 6, px = pp & 63;

  float gsc[4], bias[4];
  #pragma unroll
  for (int j = 0; j < 4; ++j) {
    int co = cog * 4 + j;
    float inv = 1.0f / sqrtf(bnv[co] + 1e-5f);
    gsc[j]  = __fmul_rn(bng[co], inv);
    bias[j] = __fsub_rn(bnb[co], __fmul_rn(__fmul_rn(bnm[co], bng[co]), inv));
  }

  bool lv  = (px >= 1);
  bool rv2 = (px <= 62);

  float vm[4][4];
  #pragma unroll
  for (int j = 0; j < 4; ++j)
    #pragma unroll
    for (int q = 0; q < 4; ++q) vm[j][q] = 0.f;

  #pragma unroll 1
  for (int t = 0; t < 4; ++t) {
    float s[4][4];
    #pragma unroll
    for (int j = 0; j < 4; ++j)
      #pragma unroll
      for (int q = 0; q < 4; ++q) s[j][q] = 0.f;

    #pragma unroll
    for (int ci = 0; ci < 2; ++ci) {
      const float* pl = x + (size_t)((n * 4 + t) * 2 + ci) * 16384;
      float q[4][6];
      #pragma unroll
      for (int i = 0; i < 4; ++i) {
        int rr = 2 * py - 1 + i;
        bool rok = (unsigned)rr < 128u;
        const float* rowp = pl + rr * 128 + 2 * px;
        float2 m  = rok          ? *(const float2*)(rowp)     : make_float2(0.f, 0.f);
        float2 lf = (rok && lv)  ? *(const float2*)(rowp - 2) : make_float2(0.f, 0.f);
        float2 rg = (rok && rv2) ? *(const float2*)(rowp + 2) : make_float2(0.f, 0.f);
        q[i][0] = lf.x; q[i][1] = lf.y; q[i][2] = m.x;
        q[i][3] = m.y;  q[i][4] = rg.x; q[i][5] = rg.y;
      }
      #pragma unroll
      for (int j = 0; j < 4; ++j) {
        const float* wp = w + (cog * 4 + j) * 18 + ci * 9;
        #pragma unroll
        for (int ky = 0; ky < 3; ++ky)
          #pragma unroll
          for (int kx = 0; kx < 3; ++kx) {
            float wv = wp[ky * 3 + kx];
            s[j][0] = fmaf(q[ky    ][kx + 1], wv, s[j][0]);
            s[j][1] = fmaf(q[ky    ][kx + 2], wv, s[j][1]);
            s[j][2] = fmaf(q[ky + 1][kx + 1], wv, s[j][2]);
            s[j][3] = fmaf(q[ky + 1][kx + 2], wv, s[j][3]);
          }
      }
    }
    ushort4 u4;
    unsigned short us[4];
    #pragma unroll
    for (int j = 0; j < 4; ++j) {
      float h0 = __fadd_rn(__fmul_rn(s[j][0], gsc[j]), bias[j]);
      float h1 = __fadd_rn(__fmul_rn(s[j][1], gsc[j]), bias[j]);
      float h2 = __fadd_rn(__fmul_rn(s[j][2], gsc[j]), bias[j]);
      float h3 = __fadd_rn(__fmul_rn(s[j][3], gsc[j]), bias[j]);
      float sp = fmaxf(fmaxf(lif_upd(vm[j][0], h0), lif_upd(vm[j][1], h1)),
                       fmaxf(lif_upd(vm[j][2], h2), lif_upd(vm[j][3], h3)));
      us[j] = (sp >= 0.5f) ? (unsigned short)0x3F80 : (unsigned short)0;
    }
    u4.x = us[0]; u4.y = us[1]; u4.z = us[2]; u4.w = us[3];
    size_t pix = (size_t)((t * 8 + n) * 66 + (py + 1)) * 66 + (px + 1);
    *(ushort4*)(out + pix * 64 + cog * 4) = u4;
  }
}

// MFMA conv(64->64) + BN + LIF + 2x2 pool, fused over t (v in regs).
// Wave: 16 x-cols x YS y-rows x 16 co. A row = lane&15 = x-offset, k = (lane>>4)*8+e = ci.
// acc row (lane>>4)*4+j = x-offset, col lane&15 = co. n = blockIdx&7 -> XCD-local.
// Epilogue packs pooled spikes via per-warp LDS into 32B stores.
template<int H, int YS>
__global__ __launch_bounds__(256, 2) void k_convM(
    const unsigned short* __restrict__ in,   // [32][H+2][H+2][64] bf16 spikes (padded)
    const unsigned short* __restrict__ wtl,  // [3][9][64][64] bf16 (this layer)
    const float* __restrict__ bng, const float* __restrict__ bnb,
    const float* __restrict__ bnm, const float* __restrict__ bnv,
    unsigned short* __restrict__ osp)        // [32][H/2+2][H/2+2][64] bf16 (padded)
{
  constexpr int W2 = H + 2;
  constexpr int HP2 = H / 2 + 2;
  constexpr int XT = H / 16;
  constexpr int YT = H / YS;

  __shared__ unsigned short lds[4][256] __attribute__((aligned(16)));

  int wrp = threadIdx.x >> 6;
  int lane = threadIdx.x & 63;
  int n = RFL(blockIdx.x & 7);
  int wid = ((blockIdx.x >> 3) << 2) | wrp;   // wave id within n
  int xt = RFL(wid % XT); int r = wid / XT;
  int yt = RFL(r % YT);
  int cog = RFL((r / YT) & 3);
  int x0 = xt * 16, y0 = yt * YS;
  int col = lane & 15, kg = lane >> 4;
  int co = cog * 16 + col;
  int laneAB = col * 64 + kg * 8;

  float inv = 1.0f / sqrtf(bnv[co] + 1e-5f);
  float g  = __fmul_rn(bng[co], inv);
  float bc = __fsub_rn(bnb[co], __fmul_rn(__fmul_rn(bnm[co], bng[co]), inv));

  float v[YS][4];
  #pragma unroll
  for (int yy = 0; yy < YS; ++yy)
    #pragma unroll
    for (int j = 0; j < 4; ++j) v[yy][j] = 0.f;

  #pragma unroll 1
  for (int t = 0; t < 4; ++t) {
    const unsigned short* ibase = in + (size_t)(t * 8 + n) * (W2 * W2 * 64);
    ffrag acc[YS];
    #pragma unroll
    for (int yy = 0; yy < YS; ++yy) {
      acc[yy][0] = 0.f; acc[yy][1] = 0.f; acc[yy][2] = 0.f; acc[yy][3] = 0.f;
    }
    #pragma unroll
    for (int tap = 0; tap < 9; ++tap) {
      const int ky = tap / 3, kx = tap % 3;
      #pragma unroll
      for (int kh = 0; kh < 2; ++kh) {
        bfrag av[YS];
        #pragma unroll
        for (int yy = 0; yy < YS; ++yy) {
          const unsigned short* au = ibase + ((y0 + yy + ky) * W2 + x0 + kx) * 64 + kh * 32;
          av[yy] = *(const bfrag*)(au + laneAB);
        }
        #pragma unroll
        for (int s = 0; s < 3; ++s) {
          const unsigned short* wu = wtl + (s * 9 + tap) * 4096 + cog * 1024 + kh * 32;
          bfrag bv = *(const bfrag*)(wu + laneAB);
          #pragma unroll
          for (int yy = 0; yy < YS; ++yy)
            acc[yy] = __builtin_amdgcn_mfma_f32_16x16x32_bf16(av[yy], bv, acc[yy], 0, 0, 0);
        }
      }
    }
    // BN + LIF + 2x2 pool (x-pairs within lane j, y-pairs across acc sets)
    #pragma unroll
    for (int yy = 0; yy < YS; yy += 2) {
      float s0[4], s1[4];
      #pragma unroll
      for (int j = 0; j < 4; ++j) {
        float h0 = __fadd_rn(__fmul_rn(acc[yy][j], g), bc);
        s0[j] = lif_upd(v[yy][j], h0);
        float h1 = __fadd_rn(__fmul_rn(acc[yy + 1][j], g), bc);
        s1[j] = lif_upd(v[yy + 1][j], h1);
      }
      #pragma unroll
      for (int b2 = 0; b2 < 2; ++b2) {
        float m = fmaxf(fmaxf(s0[2 * b2], s0[2 * b2 + 1]),
                        fmaxf(s1[2 * b2], s1[2 * b2 + 1]));
        lds[wrp][((yy >> 1) * 8 + kg * 2 + b2) * 16 + col] =
            (m >= 0.5f) ? (unsigned short)0x3F80 : (unsigned short)0;
      }
    }
    // pack: lanes < (YS/2)*8 each store one pooled pixel's 16 channels (32B)
    if (lane < (YS / 2) * 8) {
      int py = (y0 >> 1) + (lane >> 3);
      int px = (x0 >> 1) + (lane & 7);
      const uint4* sq = (const uint4*)&lds[wrp][lane * 16];
      uint4 a0 = sq[0], a1 = sq[1];
      unsigned short* dst = osp +
          ((size_t)((t * 8 + n) * HP2 + (py + 1)) * HP2 + (px + 1)) * 64 + cog * 16;
      *(uint4*)dst = a0;
      *(uint4*)(dst + 8) = a1;
    }
  }
}

// Layer 4 (H=8): MFMA conv + BN, t-parallel (no LIF). A row = (y_off,x): y_off=col>>3, x=col&7.
// Writes f32 channels-last pre4[32][8][8][64]. n = blockIdx&7.
__global__ __launch_bounds__(256, 2) void k_conv4M(
    const unsigned short* __restrict__ in,   // [32][10][10][64] bf16
    const unsigned short* __restrict__ wtl,  // [3][9][64][64] bf16 (layer 4)
    const float* __restrict__ bng, const float* __restrict__ bnb,
    const float* __restrict__ bnm, const float* __restrict__ bnv,
    float* __restrict__ pre)                 // [32][8][8][64]
{
  int wrp = threadIdx.x >> 6;
  int lane = threadIdx.x & 63;
  int n = RFL(blockIdx.x & 7);
  int t = RFL(blockIdx.x >> 3);
  int cog = RFL(wrp);
  int col = lane & 15, kg = lane >> 4;
  int co = cog * 16 + col;
  int yA = col >> 3, xA = col & 7;

  float inv = 1.0f / sqrtf(bnv[co] + 1e-5f);
  float g  = __fmul_rn(bng[co], inv);
  float bc = __fsub_rn(bnb[co], __fmul_rn(__fmul_rn(bnm[co], bng[co]), inv));

  const unsigned short* ibase = in + (size_t)(t * 8 + n) * 6400;

  ffrag acc[4];
  #pragma unroll
  for (int yy = 0; yy < 4; ++yy) {
    acc[yy][0] = 0.f; acc[yy][1] = 0.f; acc[yy][2] = 0.f; acc[yy][3] = 0.f;
  }
  #pragma unroll
  for (int tap = 0; tap < 9; ++tap) {
    const int ky = tap / 3, kx = tap % 3;
    #pragma unroll
    for (int kh = 0; kh < 2; ++kh) {
      bfrag av[4];
      #pragma unroll
      for (int yy = 0; yy < 4; ++yy) {
        const unsigned short* au =
            ibase + ((yy * 2 + yA + ky) * 10 + xA + kx) * 64 + kh * 32 + kg * 8;
        av[yy] = *(const bfrag*)au;
      }
      #pragma unroll
      for (int s = 0; s < 3; ++s) {
        const unsigned short* wu = wtl + (s * 9 + tap) * 4096 + cog * 1024 + kh * 32;
        bfrag bv = *(const bfrag*)(wu + col * 64 + kg * 8);
        #pragma unroll
        for (int yy = 0; yy < 4; ++yy)
          acc[yy] = __builtin_amdgcn_mfma_f32_16x16x32_bf16(av[yy], bv, acc[yy], 0, 0, 0);
      }
    }
  }
  #pragma unroll
  for (int yy = 0; yy < 4; ++yy)
    #pragma unroll
    for (int j = 0; j < 4; ++j) {
      int r16 = kg * 4 + j;
      int y = yy * 2 + (r16 >> 3), x = r16 & 7;
      pre[((size_t)((t * 8 + n) * 8 + y) * 8 + x) * 64 + co] =
          __fadd_rn(__fmul_rn(acc[yy][j], g), bc);
    }
}

// LIF + 2x2 pool for layer 4; channels-last in/out. out: [32][16][64] f32 (fc input).
__global__ __launch_bounds__(256) void k_lifpool8(const float* __restrict__ pre,
                                                  float* __restrict__ out) {
  int id = blockIdx.x * 256 + threadIdx.x;  // 8192
  int co = id & 63; int pp = (id >> 6) & 15; int n = id >> 10;
  int py = pp >> 2, px = pp & 3;
  float v0 = 0.f, v1 = 0.f, v2 = 0.f, v3 = 0.f;
  #pragma unroll 1
  for (int t = 0; t < 4; ++t) {
    const float* pb = pre + ((size_t)((t * 8 + n) * 8 + 2 * py) * 8 + 2 * px) * 64 + co;
    float sp = fmaxf(fmaxf(lif_upd(v0, pb[0]), lif_upd(v1, pb[64])),
                     fmaxf(lif_upd(v2, pb[8 * 64]), lif_upd(v3, pb[9 * 64])));
    out[(size_t)((t * 8 + n) * 16 + pp) * 64 + co] = sp;
  }
}

// FC1: input channels-last (pp*64+c), weight index c*16+pp -> per-lane contiguous 16 floats.
__global__ __launch_bounds__(256) void k_fc1(
    const float* __restrict__ s4, const float* __restrict__ w, float* __restrict__ out)
{
  int wv = blockIdx.x * 4 + (threadIdx.x >> 6);
  int lane = threadIdx.x & 63;
  int j = wv & 255;
  int n = wv >> 8;
  float wr[16];
  #pragma unroll
  for (int u = 0; u < 16; ++u) wr[u] = w[j * 1024 + lane * 16 + u];
  float v = 0.f;
  #pragma unroll 1
  for (int t = 0; t < 4; ++t) {
    const float* sp = s4 + (t * 8 + n) * 1024;
    float sum = 0.f;
    #pragma unroll
    for (int u = 0; u < 16; ++u) sum = fmaf(wr[u], sp[u * 64 + lane], sum);
    #pragma unroll
    for (int off = 32; off > 0; off >>= 1) sum += __shfl_xor(sum, off, 64);
    float s = lif_upd(v, sum);
    if (lane == 0) out[(t * 8 + n) * 256 + j] = s;
  }
}

// FC2: (8,256)@(110,256)^T + LIF.
__global__ __launch_bounds__(256) void k_fc2(
    const float* __restrict__ s1, const float* __restrict__ w, float* __restrict__ out)
{
  int wv = blockIdx.x * 4 + (threadIdx.x >> 6);
  int lane = threadIdx.x & 63;
  int j = wv % 110;
  int n = wv / 110;
  float wr[4];
  #pragma unroll
  for (int u = 0; u < 4; ++u) wr[u] = w[j * 256 + u * 64 + lane];
  float v = 0.f;
  #pragma unroll 1
  for (int t = 0; t < 4; ++t) {
    const float* sp = s1 + (t * 8 + n) * 256;
    float sum = 0.f;
    #pragma unroll
    for (int u = 0; u < 4; ++u) sum = fmaf(wr[u], sp[u * 64 + lane], sum);
    #pragma unroll
    for (int off = 32; off > 0; off >>= 1) sum += __shfl_xor(sum, off, 64);
    float s = lif_upd(v, sum);
    if (lane == 0) out[(t * 8 + n) * 110 + j] = s;
  }
}

// acc[n][g] = sum_t mean_{j<10} s2[t][n][g*10+j]
__global__ __launch_bounds__(128) void k_acc(const float* __restrict__ s2, float* __restrict__ out) {
  int id = threadIdx.x;
  if (id >= 88) return;
  int n = id / 11, g = id % 11;
  float a = 0.f;
  #pragma unroll 1
  for (int t = 0; t < 4; ++t) {
    float m = 0.f;
    #pragma unroll
    for (int jj = 0; jj < 10; ++jj) m = __fadd_rn(m, s2[(t * 8 + n) * 110 + g * 10 + jj]);
    a = __fadd_rn(a, __fdiv_rn(m, 10.0f));
  }
  out[n * 11 + g] = a;
}

extern "C" void kernel_launch(void* const* d_in, const int* in_sizes, int n_in,
                              void* d_out, int out_size, void* d_ws, size_t ws_size,
                              hipStream_t stream)
{
  const float* x  = (const float*)d_in[0];
  const float* w0 = (const float*)d_in[1];
  const float* wc = (const float*)d_in[2];
  const float* bg = (const float*)d_in[3];
  const float* bb = (const float*)d_in[4];
  const float* bm = (const float*)d_in[5];
  const float* bv = (const float*)d_in[6];
  const float* w1 = (const float*)d_in[7];
  const float* w2 = (const float*)d_in[8];
  float* out = (float*)d_out;

  // ---- workspace layout ----
  unsigned short* sp0 = (unsigned short*)d_ws;      // [32][66][66][64]  8,921,088
  unsigned short* sp1 = sp0 + 8921088;              // [32][34][34][64]  2,367,488
  unsigned short* sp2 = sp1 + 2367488;              // [32][18][18][64]    663,552
  unsigned short* sp3 = sp2 + 663552;               // [32][10][10][64]    204,800
  unsigned short* wt  = sp3 + 204800;               // [4][3][9][4096]     442,368
  float* fbase = (float*)((char*)d_ws + 25198592);
  float* sp4  = fbase;            // [32][16][64]      32,768
  float* pre4 = sp4 + 32768;      // [32][8][8][64]   131,072
  float* s1   = pre4 + 131072;    // [32][256]          8,192
  float* s2   = s1 + 8192;        // [32][110]          3,520
  if (ws_size < (size_t)25900800) return;

  constexpr int WTL = 3 * 9 * 4096;   // per-layer wt stride (ushorts)

  k_wsplit<<<576, 256, 0, stream>>>(wc, wt);
  k_zhalo2<66><<<260, 256, 0, stream>>>(sp0);
  k_zhalo2<34><<<132, 256, 0, stream>>>(sp1);
  k_zhalo2<18><<<68, 256, 0, stream>>>(sp2);
  k_zhalo2<10><<<36, 256, 0, stream>>>(sp3);

  k_conv0<<<2048, 256, 0, stream>>>(x, w0, bg, bb, bm, bv, sp0);

  k_convM<64, 4><<<512, 256, 0, stream>>>(sp0, wt + 0 * WTL, bg + 64,  bb + 64,  bm + 64,  bv + 64,  sp1);
  k_convM<32, 2><<<256, 256, 0, stream>>>(sp1, wt + 1 * WTL, bg + 128, bb + 128, bm + 128, bv + 128, sp2);
  k_convM<16, 2><<<64, 256, 0, stream>>>(sp2, wt + 2 * WTL, bg + 192, bb + 192, bm + 192, bv + 192, sp3);

  k_conv4M<<<32, 256, 0, stream>>>(sp3, wt + 3 * WTL, bg + 256, bb + 256, bm + 256, bv + 256, pre4);
  k_lifpool8<<<32, 256, 0, stream>>>(pre4, sp4);

  k_fc1<<<512, 256, 0, stream>>>(sp4, w1, s1);
  k_fc2<<<220, 256, 0, stream>>>(s1, w2, s2);
  k_acc<<<1, 128, 0, stream>>>(s2, out);
}

// Round 6
// 135.548 us; speedup vs baseline: 2.7119x; 1.7360x over previous
//
#include <hip/hip_runtime.h>
#include <hip/hip_bf16.h>
#include <math.h>

#define RFL(x) __builtin_amdgcn_readfirstlane(x)

typedef short bfrag __attribute__((ext_vector_type(8)));   // 8 bf16 (4 VGPR)
typedef float ffrag __attribute__((ext_vector_type(4)));   // 4 f32 acc

// LIF: v = v + (x - v)/2 ; s = (v >= 1) ; v = s ? 0 : v   (exact rounding match)
static __device__ __forceinline__ float lif_upd(float& v, float x) {
  v = __fadd_rn(v, __fmul_rn(__fsub_rn(x, v), 0.5f));
  float s = (v >= 1.0f) ? 1.0f : 0.0f;
  v = (v >= 1.0f) ? 0.0f : v;
  return s;
}

static __device__ __forceinline__ unsigned short f2bf(float x) {
  __hip_bfloat16 h = __float2bfloat16(x);
  return *reinterpret_cast<unsigned short*>(&h);
}
static __device__ __forceinline__ float bf2f(unsigned short u) {
  __hip_bfloat16 h = *reinterpret_cast<__hip_bfloat16*>(&u);
  return __bfloat162float(h);
}

// Split conv weights (4 layers, 64x64x3x3 f32) into 3 bf16 components, transposed to
// wt[((l*3+s)*9+tap)*4096 + co*64 + ci].
__global__ __launch_bounds__(256) void k_wsplit(const float* __restrict__ wc,
                                                unsigned short* __restrict__ wt) {
  int id = blockIdx.x * 256 + threadIdx.x;   // 147456 total
  int tap = id % 9; int r = id / 9;
  int ci = r & 63; r >>= 6;
  int co = r & 63; int l = r >> 6;
  float w = wc[(size_t)(((l * 64 + co) * 64 + ci) * 9) + tap];
  unsigned short h0 = f2bf(w);  float r1 = __fsub_rn(w, bf2f(h0));
  unsigned short h1 = f2bf(r1); float r2 = __fsub_rn(r1, bf2f(h1));
  unsigned short h2 = f2bf(r2);
  size_t base = (size_t)((l * 3) * 9 + tap) * 4096 + co * 64 + ci;
  wt[base] = h0;
  wt[base + 9 * 4096] = h1;
  wt[base + 18 * 4096] = h2;
}

// One launch: zero halo rings (x64 ch) of all four padded spike buffers.
static __device__ __forceinline__ void zring(unsigned short* buf, int W2, int idx) {
  int PERIM = 4 * W2 - 4;
  int c8 = idx & 7;
  int r = idx >> 3;
  int p = r % PERIM; int pl = r / PERIM;
  int row, col;
  if (p < W2)            { row = 0;      col = p; }
  else if (p < 2 * W2)   { row = W2 - 1; col = p - W2; }
  else { int q = p - 2 * W2; row = 1 + (q >> 1); col = (q & 1) ? (W2 - 1) : 0; }
  *(uint4*)(buf + ((size_t)(pl * W2 + row) * W2 + col) * 64 + c8 * 8) =
      make_uint4(0u, 0u, 0u, 0u);
}
__global__ __launch_bounds__(256) void k_zhaloAll(unsigned short* __restrict__ ws0) {
  int id = blockIdx.x * 256 + threadIdx.x;
  if (id < 66560)            zring(ws0,            66, id);
  else if (id < 100352)      zring(ws0 + 8921088,  34, id - 66560);
  else if (id < 117760)      zring(ws0 + 11288576, 18, id - 100352);
  else if (id < 126976)      zring(ws0 + 11952128, 10, id - 117760);
}

// Layer 0: fused conv(2->64) + BN + LIF + 2x2 maxpool. Writes channels-last bf16 spikes
// into padded [32][66][66][64] (interior at +1,+1).
__global__ __launch_bounds__(256, 4) void k_conv0(
    const float* __restrict__ x,   // [8][4][2][128][128]
    const float* __restrict__ w,   // [64][2][3][3]
    const float* __restrict__ bng, const float* __restrict__ bnb,
    const float* __restrict__ bnm, const float* __restrict__ bnv,
    unsigned short* __restrict__ out)
{
  int n   = RFL(blockIdx.x & 7);
  int b2  = blockIdx.x >> 3;          // [0,256)
  int cog = RFL(b2 & 15);             // 4-channel group
  int pp  = ((b2 >> 4) << 8) | threadIdx.x;   // [0,4096) pooled positions
  int py = pp >> 6, px = pp & 63;

  float gsc[4], bias[4];
  #pragma unroll
  for (int j = 0; j < 4; ++j) {
    int co = cog * 4 + j;
    float inv = 1.0f / sqrtf(bnv[co] + 1e-5f);
    gsc[j]  = __fmul_rn(bng[co], inv);
    bias[j] = __fsub_rn(bnb[co], __fmul_rn(__fmul_rn(bnm[co], bng[co]), inv));
  }

  bool lv  = (px >= 1);
  bool rv2 = (px <= 62);

  float vm[4][4];
  #pragma unroll
  for (int j = 0; j < 4; ++j)
    #pragma unroll
    for (int q = 0; q < 4; ++q) vm[j][q] = 0.f;

  #pragma unroll 1
  for (int t = 0; t < 4; ++t) {
    float s[4][4];
    #pragma unroll
    for (int j = 0; j < 4; ++j)
      #pragma unroll
      for (int q = 0; q < 4; ++q) s[j][q] = 0.f;

    #pragma unroll
    for (int ci = 0; ci < 2; ++ci) {
      const float* pl = x + (size_t)((n * 4 + t) * 2 + ci) * 16384;
      float q[4][6];
      #pragma unroll
      for (int i = 0; i < 4; ++i) {
        int rr = 2 * py - 1 + i;
        bool rok = (unsigned)rr < 128u;
        const float* rowp = pl + rr * 128 + 2 * px;
        float2 m  = rok          ? *(const float2*)(rowp)     : make_float2(0.f, 0.f);
        float2 lf = (rok && lv)  ? *(const float2*)(rowp - 2) : make_float2(0.f, 0.f);
        float2 rg = (rok && rv2) ? *(const float2*)(rowp + 2) : make_float2(0.f, 0.f);
        q[i][0] = lf.x; q[i][1] = lf.y; q[i][2] = m.x;
        q[i][3] = m.y;  q[i][4] = rg.x; q[i][5] = rg.y;
      }
      #pragma unroll
      for (int j = 0; j < 4; ++j) {
        const float* wp = w + (cog * 4 + j) * 18 + ci * 9;
        #pragma unroll
        for (int ky = 0; ky < 3; ++ky)
          #pragma unroll
          for (int kx = 0; kx < 3; ++kx) {
            float wv = wp[ky * 3 + kx];
            s[j][0] = fmaf(q[ky    ][kx + 1], wv, s[j][0]);
            s[j][1] = fmaf(q[ky    ][kx + 2], wv, s[j][1]);
            s[j][2] = fmaf(q[ky + 1][kx + 1], wv, s[j][2]);
            s[j][3] = fmaf(q[ky + 1][kx + 2], wv, s[j][3]);
          }
      }
    }
    ushort4 u4;
    unsigned short us[4];
    #pragma unroll
    for (int j = 0; j < 4; ++j) {
      float h0 = __fadd_rn(__fmul_rn(s[j][0], gsc[j]), bias[j]);
      float h1 = __fadd_rn(__fmul_rn(s[j][1], gsc[j]), bias[j]);
      float h2 = __fadd_rn(__fmul_rn(s[j][2], gsc[j]), bias[j]);
      float h3 = __fadd_rn(__fmul_rn(s[j][3], gsc[j]), bias[j]);
      float sp = fmaxf(fmaxf(lif_upd(vm[j][0], h0), lif_upd(vm[j][1], h1)),
                       fmaxf(lif_upd(vm[j][2], h2), lif_upd(vm[j][3], h3)));
      us[j] = (sp >= 0.5f) ? (unsigned short)0x3F80 : (unsigned short)0;
    }
    u4.x = us[0]; u4.y = us[1]; u4.z = us[2]; u4.w = us[3];
    size_t pix = (size_t)((t * 8 + n) * 66 + (py + 1)) * 66 + (px + 1);
    *(ushort4*)(out + pix * 64 + cog * 4) = u4;
  }
}

// MFMA conv(64->64)+BN+LIF+2x2 pool, LDS-staged & placement-agnostic.
// Block = 4 waves = 4 cog (all 64 co) x 16 out-x x 2 out-y, ALL 4 timesteps.
// Stage tile[4t][4rows][18px][64ch] bf16 (XOR-swizzled 16B slots) ONCE; loop
// taps with t innermost so each B-frag loads once. Full-line packed output.
template<int H>
__global__ __launch_bounds__(256, 2) void k_convT(
    const unsigned short* __restrict__ in,   // [32][H+2][H+2][64] padded spikes
    const unsigned short* __restrict__ wtl,  // [3][9][64][64] bf16 (this layer)
    const float* __restrict__ bng, const float* __restrict__ bnb,
    const float* __restrict__ bnm, const float* __restrict__ bnv,
    unsigned short* __restrict__ osp)        // [32][H/2+2][H/2+2][64] padded
{
  constexpr int W2 = H + 2;
  constexpr int HP2 = H / 2 + 2;
  constexpr int XT = H / 16;
  constexpr int YT = H / 2;                  // YS = 2
  constexpr int XS = 18;
  constexpr int TILE = 4 * 4 * XS * 64;      // 18432 ushorts (36.9 KB)
  constexpr int CHUNKS = TILE / 8;           // 2304 16B chunks

  __shared__ unsigned short tile[TILE];
  __shared__ unsigned short pack[4 * 8 * 64];  // [t][ppx][ch]

  int tid = threadIdx.x;
  int lane = tid & 63;
  int cog = tid >> 6;                        // wave = cog
  int bid = blockIdx.x;
  int n  = RFL(bid & 7);
  int rest = bid >> 3;
  int xt = RFL(rest % XT);
  int yt = RFL(rest / XT);
  int x0 = xt * 16, y0 = yt * 2;
  int col = lane & 15, kg = lane >> 4;
  int co = cog * 16 + col;

  float inv = 1.0f / sqrtf(bnv[co] + 1e-5f);
  float g  = __fmul_rn(bng[co], inv);
  float bc = __fsub_rn(bnb[co], __fmul_rn(__fmul_rn(bnm[co], bng[co]), inv));

  // ---- stage all 4 timesteps ----
  #pragma unroll
  for (int it = 0; it < CHUNKS / 256; ++it) {
    int c = it * 256 + tid;
    int c16 = c & 7;
    int pix = c >> 3;              // (tt*4+row)*18 + pxl
    int pxl = pix % XS;
    int rw  = pix / XS;            // [0,16)
    int row = rw & 3, tt = rw >> 2;
    const unsigned short* s = in +
        ((size_t)(tt * 8 + n) * W2 * W2 + (size_t)(y0 + row) * W2 + (x0 + pxl)) * 64 + c16 * 8;
    uint4 d = *(const uint4*)s;
    *(uint4*)&tile[pix * 64 + ((c16 * 8) ^ ((pxl & 7) << 3))] = d;
  }
  __syncthreads();

  // ---- MFMA: taps outer, t inner (B loaded once) ----
  ffrag acc[4][2];
  #pragma unroll
  for (int tt = 0; tt < 4; ++tt)
    #pragma unroll
    for (int yy = 0; yy < 2; ++yy) {
      acc[tt][yy][0] = 0.f; acc[tt][yy][1] = 0.f;
      acc[tt][yy][2] = 0.f; acc[tt][yy][3] = 0.f;
    }

  #pragma unroll
  for (int tap = 0; tap < 9; ++tap) {
    const int ky = tap / 3, kx = tap % 3;
    const int pxl = kx + col;
    const int swz = (pxl & 7) << 3;
    #pragma unroll
    for (int kh = 0; kh < 2; ++kh) {
      bfrag av[4][2];
      #pragma unroll
      for (int tt = 0; tt < 4; ++tt)
        #pragma unroll
        for (int yy = 0; yy < 2; ++yy)
          av[tt][yy] = *(const bfrag*)&tile[((tt * 4 + yy + ky) * XS + pxl) * 64 +
                                            ((kh * 32 + kg * 8) ^ swz)];
      #pragma unroll
      for (int s = 0; s < 3; ++s) {
        bfrag bv = *(const bfrag*)(wtl + (size_t)(s * 9 + tap) * 4096 +
                                   cog * 1024 + col * 64 + kh * 32 + kg * 8);
        #pragma unroll
        for (int tt = 0; tt < 4; ++tt)
          #pragma unroll
          for (int yy = 0; yy < 2; ++yy)
            acc[tt][yy] = __builtin_amdgcn_mfma_f32_16x16x32_bf16(av[tt][yy], bv,
                                                                  acc[tt][yy], 0, 0, 0);
      }
    }
  }

  // ---- BN + LIF (t-sequential) + 2x2 pool -> pack ----
  float v[2][4];
  #pragma unroll
  for (int yy = 0; yy < 2; ++yy)
    #pragma unroll
    for (int j = 0; j < 4; ++j) v[yy][j] = 0.f;

  #pragma unroll
  for (int tt = 0; tt < 4; ++tt) {
    float s0[4], s1[4];
    #pragma unroll
    for (int j = 0; j < 4; ++j) {
      s0[j] = lif_upd(v[0][j], __fadd_rn(__fmul_rn(acc[tt][0][j], g), bc));
      s1[j] = lif_upd(v[1][j], __fadd_rn(__fmul_rn(acc[tt][1][j], g), bc));
    }
    #pragma unroll
    for (int b2 = 0; b2 < 2; ++b2) {
      float m = fmaxf(fmaxf(s0[2 * b2], s0[2 * b2 + 1]),
                      fmaxf(s1[2 * b2], s1[2 * b2 + 1]));
      pack[(tt * 8 + kg * 2 + b2) * 64 + co] =
          (m >= 0.5f) ? (unsigned short)0x3F80 : (unsigned short)0;
    }
  }
  __syncthreads();

  // ---- full-line write: 256 threads = 4t x 8ppx x 8 chunks ----
  {
    int c16 = tid & 7, ppx = (tid >> 3) & 7, tt = tid >> 6;
    uint4 d = *(const uint4*)&pack[(tt * 8 + ppx) * 64 + c16 * 8];
    *(uint4*)(osp + ((size_t)((tt * 8 + n) * HP2 + (yt + 1)) * HP2 +
                     (xt * 8 + ppx + 1)) * 64 + c16 * 8) = d;
  }
}

// Layer 4 (H=8): MFMA conv + BN, t-parallel (no LIF). A row=(y_off,x). n = blockIdx&7.
__global__ __launch_bounds__(256, 2) void k_conv4M(
    const unsigned short* __restrict__ in,   // [32][10][10][64] bf16
    const unsigned short* __restrict__ wtl,  // [3][9][64][64] bf16 (layer 4)
    const float* __restrict__ bng, const float* __restrict__ bnb,
    const float* __restrict__ bnm, const float* __restrict__ bnv,
    float* __restrict__ pre)                 // [32][8][8][64]
{
  int wrp = threadIdx.x >> 6;
  int lane = threadIdx.x & 63;
  int n = RFL(blockIdx.x & 7);
  int t = RFL(blockIdx.x >> 3);
  int cog = RFL(wrp);
  int col = lane & 15, kg = lane >> 4;
  int co = cog * 16 + col;
  int yA = col >> 3, xA = col & 7;

  float inv = 1.0f / sqrtf(bnv[co] + 1e-5f);
  float g  = __fmul_rn(bng[co], inv);
  float bc = __fsub_rn(bnb[co], __fmul_rn(__fmul_rn(bnm[co], bng[co]), inv));

  const unsigned short* ibase = in + (size_t)(t * 8 + n) * 6400;

  ffrag acc[4];
  #pragma unroll
  for (int yy = 0; yy < 4; ++yy) {
    acc[yy][0] = 0.f; acc[yy][1] = 0.f; acc[yy][2] = 0.f; acc[yy][3] = 0.f;
  }
  #pragma unroll
  for (int tap = 0; tap < 9; ++tap) {
    const int ky = tap / 3, kx = tap % 3;
    #pragma unroll
    for (int kh = 0; kh < 2; ++kh) {
      bfrag av[4];
      #pragma unroll
      for (int yy = 0; yy < 4; ++yy) {
        const unsigned short* au =
            ibase + ((yy * 2 + yA + ky) * 10 + xA + kx) * 64 + kh * 32 + kg * 8;
        av[yy] = *(const bfrag*)au;
      }
      #pragma unroll
      for (int s = 0; s < 3; ++s) {
        const unsigned short* wu = wtl + (s * 9 + tap) * 4096 + cog * 1024 + kh * 32;
        bfrag bv = *(const bfrag*)(wu + col * 64 + kg * 8);
        #pragma unroll
        for (int yy = 0; yy < 4; ++yy)
          acc[yy] = __builtin_amdgcn_mfma_f32_16x16x32_bf16(av[yy], bv, acc[yy], 0, 0, 0);
      }
    }
  }
  #pragma unroll
  for (int yy = 0; yy < 4; ++yy)
    #pragma unroll
    for (int j = 0; j < 4; ++j) {
      int r16 = kg * 4 + j;
      int y = yy * 2 + (r16 >> 3), x = r16 & 7;
      pre[((size_t)((t * 8 + n) * 8 + y) * 8 + x) * 64 + co] =
          __fadd_rn(__fmul_rn(acc[yy][j], g), bc);
    }
}

// LIF + 2x2 pool for layer 4; channels-last in/out. out: [32][16][64] f32 (fc input).
__global__ __launch_bounds__(256) void k_lifpool8(const float* __restrict__ pre,
                                                  float* __restrict__ out) {
  int id = blockIdx.x * 256 + threadIdx.x;  // 8192
  int co = id & 63; int pp = (id >> 6) & 15; int n = id >> 10;
  int py = pp >> 2, px = pp & 3;
  float v0 = 0.f, v1 = 0.f, v2 = 0.f, v3 = 0.f;
  #pragma unroll 1
  for (int t = 0; t < 4; ++t) {
    const float* pb = pre + ((size_t)((t * 8 + n) * 8 + 2 * py) * 8 + 2 * px) * 64 + co;
    float sp = fmaxf(fmaxf(lif_upd(v0, pb[0]), lif_upd(v1, pb[64])),
                     fmaxf(lif_upd(v2, pb[8 * 64]), lif_upd(v3, pb[9 * 64])));
    out[(size_t)((t * 8 + n) * 16 + pp) * 64 + co] = sp;
  }
}

// FC1: input channels-last (pp*64+c), weight index c*16+pp -> per-lane contiguous 16 floats.
__global__ __launch_bounds__(256) void k_fc1(
    const float* __restrict__ s4, const float* __restrict__ w, float* __restrict__ out)
{
  int wv = blockIdx.x * 4 + (threadIdx.x >> 6);
  int lane = threadIdx.x & 63;
  int j = wv & 255;
  int n = wv >> 8;
  float wr[16];
  #pragma unroll
  for (int u = 0; u < 16; ++u) wr[u] = w[j * 1024 + lane * 16 + u];
  float v = 0.f;
  #pragma unroll 1
  for (int t = 0; t < 4; ++t) {
    const float* sp = s4 + (t * 8 + n) * 1024;
    float sum = 0.f;
    #pragma unroll
    for (int u = 0; u < 16; ++u) sum = fmaf(wr[u], sp[u * 64 + lane], sum);
    #pragma unroll
    for (int off = 32; off > 0; off >>= 1) sum += __shfl_xor(sum, off, 64);
    float s = lif_upd(v, sum);
    if (lane == 0) out[(t * 8 + n) * 256 + j] = s;
  }
}

// FC2: (8,256)@(110,256)^T + LIF.
__global__ __launch_bounds__(256) void k_fc2(
    const float* __restrict__ s1, const float* __restrict__ w, float* __restrict__ out)
{
  int wv = blockIdx.x * 4 + (threadIdx.x >> 6);
  int lane = threadIdx.x & 63;
  int j = wv % 110;
  int n = wv / 110;
  float wr[4];
  #pragma unroll
  for (int u = 0; u < 4; ++u) wr[u] = w[j * 256 + u * 64 + lane];
  float v = 0.f;
  #pragma unroll 1
  for (int t = 0; t < 4; ++t) {
    const float* sp = s1 + (t * 8 + n) * 256;
    float sum = 0.f;
    #pragma unroll
    for (int u = 0; u < 4; ++u) sum = fmaf(wr[u], sp[u * 64 + lane], sum);
    #pragma unroll
    for (int off = 32; off > 0; off >>= 1) sum += __shfl_xor(sum, off, 64);
    float s = lif_upd(v, sum);
    if (lane == 0) out[(t * 8 + n) * 110 + j] = s;
  }
}

// acc[n][g] = sum_t mean_{j<10} s2[t][n][g*10+j]
__global__ __launch_bounds__(128) void k_acc(const float* __restrict__ s2, float* __restrict__ out) {
  int id = threadIdx.x;
  if (id >= 88) return;
  int n = id / 11, g = id % 11;
  float a = 0.f;
  #pragma unroll 1
  for (int t = 0; t < 4; ++t) {
    float m = 0.f;
    #pragma unroll
    for (int jj = 0; jj < 10; ++jj) m = __fadd_rn(m, s2[(t * 8 + n) * 110 + g * 10 + jj]);
    a = __fadd_rn(a, __fdiv_rn(m, 10.0f));
  }
  out[n * 11 + g] = a;
}

extern "C" void kernel_launch(void* const* d_in, const int* in_sizes, int n_in,
                              void* d_out, int out_size, void* d_ws, size_t ws_size,
                              hipStream_t stream)
{
  const float* x  = (const float*)d_in[0];
  const float* w0 = (const float*)d_in[1];
  const float* wc = (const float*)d_in[2];
  const float* bg = (const float*)d_in[3];
  const float* bb = (const float*)d_in[4];
  const float* bm = (const float*)d_in[5];
  const float* bv = (const float*)d_in[6];
  const float* w1 = (const float*)d_in[7];
  const float* w2 = (const float*)d_in[8];
  float* out = (float*)d_out;

  // ---- workspace layout ----
  unsigned short* sp0 = (unsigned short*)d_ws;      // [32][66][66][64]  8,921,088
  unsigned short* sp1 = sp0 + 8921088;              // [32][34][34][64]  2,367,488
  unsigned short* sp2 = sp1 + 2367488;              // [32][18][18][64]    663,552
  unsigned short* sp3 = sp2 + 663552;               // [32][10][10][64]    204,800
  unsigned short* wt  = sp3 + 204800;               // [4][3][9][4096]     442,368
  float* fbase = (float*)((char*)d_ws + 25198592);
  float* sp4  = fbase;            // [32][16][64]      32,768
  float* pre4 = sp4 + 32768;      // [32][8][8][64]   131,072
  float* s1   = pre4 + 131072;    // [32][256]          8,192
  float* s2   = s1 + 8192;        // [32][110]          3,520
  if (ws_size < (size_t)25900800) return;

  constexpr int WTL = 3 * 9 * 4096;   // per-layer wt stride (ushorts)

  k_wsplit<<<576, 256, 0, stream>>>(wc, wt);
  k_zhaloAll<<<496, 256, 0, stream>>>(sp0);

  k_conv0<<<2048, 256, 0, stream>>>(x, w0, bg, bb, bm, bv, sp0);

  k_convT<64><<<1024, 256, 0, stream>>>(sp0, wt + 0 * WTL, bg + 64,  bb + 64,  bm + 64,  bv + 64,  sp1);
  k_convT<32><<<256, 256, 0, stream>>>(sp1, wt + 1 * WTL, bg + 128, bb + 128, bm + 128, bv + 128, sp2);
  k_convT<16><<<64, 256, 0, stream>>>(sp2, wt + 2 * WTL, bg + 192, bb + 192, bm + 192, bv + 192, sp3);

  k_conv4M<<<32, 256, 0, stream>>>(sp3, wt + 3 * WTL, bg + 256, bb + 256, bm + 256, bv + 256, pre4);
  k_lifpool8<<<32, 256, 0, stream>>>(pre4, sp4);

  k_fc1<<<512, 256, 0, stream>>>(sp4, w1, s1);
  k_fc2<<<220, 256, 0, stream>>>(s1, w2, s2);
  k_acc<<<1, 128, 0, stream>>>(s2, out);
}